// Round 2
// baseline (110.087 us; speedup 1.0000x reference)
//
#include <hip/hip_runtime.h>
#include <hip/hip_bf16.h>

#define B_ 8192
#define C_ 10000
#define D_ 128
#define CPAD 10112   // 79 * 128
#define NTILES 79
#define NSTRIPS 8
#define STRIPW 10    // strips 0..6 -> 10 tiles, strip 7 -> 9 tiles

typedef float f32x4 __attribute__((ext_vector_type(4)));
typedef short s16x8 __attribute__((ext_vector_type(8)));

// ---------------- ws layout (float offsets) ----------------
// counts    : [0, 10240)
// sumx/cnew : [10240, 1290240)
// git_row   : [1290240, 1298432)   (zeroed prefix ends here)
// xnorm     : [1298432, 1306624)
// cent_val  : [1306624, 1314816)
// cnorm     : [1314816, 1325056)   (CPAD, pad = 1e30)
// x_bf16    : byte 5,300,224
// cnew_bf16 : byte 7,397,376

__global__ void scatter_xprep(const float* __restrict__ x, const int* __restrict__ labels,
                              float* __restrict__ counts, float* __restrict__ sumx,
                              float* __restrict__ xnorm, __hip_bfloat16* __restrict__ xb) {
    int i = blockIdx.x;
    int d = threadIdx.x;
    int l = labels[i];
    float v = x[i * D_ + d];
    atomicAdd(&sumx[l * D_ + d], v);
    if (d == 0) atomicAdd(&counts[l], 1.0f);
    xb[i * D_ + d] = __float2bfloat16(v);
    float s = v * v;
    #pragma unroll
    for (int m = 1; m < 64; m <<= 1) s += __shfl_xor(s, m);
    __shared__ float w2[2];
    if ((d & 63) == 0) w2[d >> 6] = s;
    __syncthreads();
    if (d == 0) xnorm[i] = w2[0] + w2[1];
}

__global__ void center_update(const float* __restrict__ centers, const float* __restrict__ counts,
                              float* __restrict__ sumx_cnew, float* __restrict__ cnorm,
                              __hip_bfloat16* __restrict__ cb, const float* __restrict__ lr) {
    int c = blockIdx.x;
    int d = threadIdx.x;
    if (c >= C_) {
        cb[c * D_ + d] = __float2bfloat16(0.0f);
        if (d == 0) cnorm[c] = 1e30f;
        return;
    }
    float cnt = counts[c];
    float cv  = centers[c * D_ + d];
    float sx  = sumx_cnew[c * D_ + d];
    float delta = (cnt * cv - sx) / (1.0f + cnt);
    float cn = cv - lr[0] * delta;
    sumx_cnew[c * D_ + d] = cn;
    cb[c * D_ + d] = __float2bfloat16(cn);
    float s = cn * cn;
    #pragma unroll
    for (int m = 1; m < 64; m <<= 1) s += __shfl_xor(s, m);
    __shared__ float w2[2];
    if ((d & 63) == 0) w2[d >> 6] = s;
    __syncthreads();
    if (d == 0) cnorm[c] = w2[0] + w2[1];
}

__global__ void center_vals_k(const float* __restrict__ x, const int* __restrict__ labels,
                              const float* __restrict__ cnew, float* __restrict__ cent_val) {
    int w = threadIdx.x >> 6, lane = threadIdx.x & 63;
    int i = blockIdx.x * 4 + w;
    int l = labels[i];
    float d1 = x[i * D_ + lane]      - cnew[l * D_ + lane];
    float d2 = x[i * D_ + lane + 64] - cnew[l * D_ + lane + 64];
    float s = d1 * d1 + d2 * d2;
    #pragma unroll
    for (int m = 1; m < 64; m <<= 1) s += __shfl_xor(s, m);
    if (lane == 0) cent_val[i] = s;
}

// Strip-mined fused GEMM+git.
// Block = (strip, bm): A frags (128 rows x K=128) live in registers; loop over
// the strip's B tiles with double-buffered LDS (reg-staged, loads overlapped
// with compute); git accumulates in registers across the strip.
__global__ void __launch_bounds__(256, 2)
gemm_git(const __hip_bfloat16* __restrict__ xb, const __hip_bfloat16* __restrict__ cb,
         const float* __restrict__ xnorm, const float* __restrict__ cnorm,
         float* __restrict__ git_row) {
    __shared__ uint4 ldsB[2][2048];   // 2 x 32KB, XOR-swizzled

    int tid = threadIdx.x;
    int strip = blockIdx.x;           // consecutive blocks share strip? No: x fastest
    int bm = blockIdx.y;
    int bn0 = strip * STRIPW;
    int nt = (strip == NSTRIPS - 1) ? (NTILES - bn0) : STRIPW;

    int w = tid >> 6, lane = tid & 63;
    int wm = w >> 1, wn = w & 1;
    int lr_ = lane & 15, lg = lane >> 4;

    // ---- A fragments: row = bm*128 + wm*64 + f*16 + lr_, chunk = kk*4+lg ----
    const s16x8* gx = (const s16x8*)xb;     // row stride = 16 chunks
    s16x8 af[4][4];
    #pragma unroll
    for (int kk = 0; kk < 4; kk++)
        #pragma unroll
        for (int f = 0; f < 4; f++) {
            int row = bm * 128 + wm * 64 + f * 16 + lr_;
            af[kk][f] = gx[row * 16 + kk * 4 + lg];
        }

    // ---- per-lane xnorm (+1 folded): rows owned in C/D layout ----
    float xn1[4][4];
    #pragma unroll
    for (int fm = 0; fm < 4; fm++)
        #pragma unroll
        for (int r = 0; r < 4; r++)
            xn1[fm][r] = 1.0f + xnorm[bm * 128 + wm * 64 + fm * 16 + lg * 4 + r];

    float gitsum[4][4] = {};

    const uint4* gB = (const uint4*)cb;

    // prologue: stage tile 0
    {
        uint4 st[8];
        #pragma unroll
        for (int p = 0; p < 8; p++) {
            int idx = tid + p * 256;
            st[p] = gB[(bn0 * 128 + (idx >> 4)) * 16 + (idx & 15)];
        }
        #pragma unroll
        for (int p = 0; p < 8; p++) {
            int idx = tid + p * 256;
            int row = idx >> 4, ch = idx & 15;
            ldsB[0][row * 16 + (ch ^ (row & 7))] = st[p];
        }
    }
    __syncthreads();

    int cur = 0;
    for (int t = 0; t < nt; ++t) {
        bool more = (t + 1 < nt);
        uint4 st[8];
        if (more) {
            #pragma unroll
            for (int p = 0; p < 8; p++) {
                int idx = tid + p * 256;
                st[p] = gB[((bn0 + t + 1) * 128 + (idx >> 4)) * 16 + (idx & 15)];
            }
        }

        // compute on ldsB[cur]
        f32x4 acc[4][4] = {};
        #pragma unroll
        for (int kk = 0; kk < 4; kk++) {
            s16x8 bfr[4];
            int kc = kk * 4 + lg;
            #pragma unroll
            for (int fn = 0; fn < 4; fn++) {
                int rowB = wn * 64 + fn * 16 + lr_;
                bfr[fn] = *(const s16x8*)&ldsB[cur][rowB * 16 + (kc ^ (rowB & 7))];
            }
            #pragma unroll
            for (int fm = 0; fm < 4; fm++)
                #pragma unroll
                for (int fn = 0; fn < 4; fn++)
                    acc[fm][fn] = __builtin_amdgcn_mfma_f32_16x16x32_bf16(af[kk][fm], bfr[fn], acc[fm][fn], 0, 0, 0);
        }

        // epilogue: git += 1/(1 + dist), accumulate in registers
        int bnc = bn0 + t;
        float cn[4];
        #pragma unroll
        for (int fn = 0; fn < 4; fn++)
            cn[fn] = cnorm[bnc * 128 + wn * 64 + fn * 16 + lr_];
        #pragma unroll
        for (int fm = 0; fm < 4; fm++)
            #pragma unroll
            for (int r = 0; r < 4; r++) {
                float base = xn1[fm][r];
                #pragma unroll
                for (int fn = 0; fn < 4; fn++) {
                    float dist = base + cn[fn] - 2.0f * acc[fm][fn][r];
                    gitsum[fm][r] += __builtin_amdgcn_rcpf(dist);
                }
            }

        __syncthreads();
        if (more) {
            #pragma unroll
            for (int p = 0; p < 8; p++) {
                int idx = tid + p * 256;
                int row = idx >> 4, ch = idx & 15;
                ldsB[cur ^ 1][row * 16 + (ch ^ (row & 7))] = st[p];
            }
            __syncthreads();
        }
        cur ^= 1;
    }

    // final reduce over lr_ (16 lanes summing different fn-columns)
    #pragma unroll
    for (int fm = 0; fm < 4; fm++)
        #pragma unroll
        for (int r = 0; r < 4; r++) {
            float s = gitsum[fm][r];
            s += __shfl_xor(s, 1); s += __shfl_xor(s, 2);
            s += __shfl_xor(s, 4); s += __shfl_xor(s, 8);
            if (lr_ == 0)
                atomicAdd(&git_row[bm * 128 + wm * 64 + fm * 16 + lg * 4 + r], s);
        }
}

__global__ void final_reduce(const float* __restrict__ cent_val, const float* __restrict__ git_row,
                             float* __restrict__ out) {
    int tid = threadIdx.x;
    float cl = 0.0f, gl = 0.0f;
    for (int i = tid; i < B_; i += 256) {
        float cv = cent_val[i];
        cl += fminf(fmaxf(cv, 1e-12f), 1e12f);
        float g = git_row[i] - 1.0f / (1.0f + cv);
        gl += fminf(fmaxf(g, 1e-12f), 1e12f);
    }
    #pragma unroll
    for (int m = 1; m < 64; m <<= 1) { cl += __shfl_xor(cl, m); gl += __shfl_xor(gl, m); }
    __shared__ float scl[4], sgl[4];
    if ((tid & 63) == 0) { scl[tid >> 6] = cl; sgl[tid >> 6] = gl; }
    __syncthreads();
    if (tid == 0) {
        out[0] = (scl[0] + scl[1] + scl[2] + scl[3]) / (float)B_;
        out[1] = (sgl[0] + sgl[1] + sgl[2] + sgl[3]) / (float)B_;
    }
}

extern "C" void kernel_launch(void* const* d_in, const int* in_sizes, int n_in,
                              void* d_out, int out_size, void* d_ws, size_t ws_size,
                              hipStream_t stream) {
    const float* x       = (const float*)d_in[0];
    const int*   labels  = (const int*)d_in[1];
    const float* centers = (const float*)d_in[2];
    const float* lr      = (const float*)d_in[3];

    float* ws       = (float*)d_ws;
    float* counts   = ws;
    float* sumx     = ws + 10240;
    float* git_row  = ws + 1290240;
    float* xnorm    = ws + 1298432;
    float* cent_val = ws + 1306624;
    float* cnorm    = ws + 1314816;
    __hip_bfloat16* xb = (__hip_bfloat16*)((char*)d_ws + 5300224);
    __hip_bfloat16* cb = (__hip_bfloat16*)((char*)d_ws + 7397376);
    float* out = (float*)d_out;

    hipMemsetAsync(d_ws, 0, (size_t)1298432 * 4, stream);

    scatter_xprep<<<B_, 128, 0, stream>>>(x, labels, counts, sumx, xnorm, xb);
    center_update<<<CPAD, 128, 0, stream>>>(centers, counts, sumx, cnorm, cb, lr);
    center_vals_k<<<B_ / 4, 256, 0, stream>>>(x, labels, sumx, cent_val);
    gemm_git<<<dim3(NSTRIPS, B_ / 128), 256, 0, stream>>>(xb, cb, xnorm, cnorm, git_row);
    final_reduce<<<1, 256, 0, stream>>>(cent_val, git_row, out);
}

// Round 3
// 77.386 us; speedup vs baseline: 1.4226x; 1.4226x over previous
//
#include <hip/hip_runtime.h>
#include <hip/hip_bf16.h>

#define B_ 8192
#define C_ 10000
#define D_ 128
#define CPAD 10112      // 158 * 64
#define NT_TOT 158      // 64-col tiles
#define NSTRIP 16
#define STRIPW 10       // strips 0..14 -> 10 tiles, strip 15 -> 8

typedef float f32x4 __attribute__((ext_vector_type(4)));
typedef short s16x8 __attribute__((ext_vector_type(8)));

// ---------------- ws layout (float offsets) ----------------
// counts    : [0, 10240)
// sumx/cnew : [10240, 1290240)
// git_row   : [1290240, 1298432)   (zeroed prefix ends here: 5,193,728 B)
// xnorm     : [1298432, 1306624)
// cent_val  : [1306624, 1314816)
// cnorm     : [1314816, 1325056)   (CPAD, pad = 1e30)
// x_bf16    : byte 5,300,224
// cnew_bf16 : byte 7,397,376

// wave-per-row, float2 per lane; no LDS, no syncthreads
__global__ void scatter_xprep(const float* __restrict__ x, const int* __restrict__ labels,
                              float* __restrict__ counts, float* __restrict__ sumx,
                              float* __restrict__ xnorm, __hip_bfloat16* __restrict__ xb) {
    int tid = threadIdx.x;
    int w = tid >> 6, lane = tid & 63;
    int i = blockIdx.x * 4 + w;
    int l = labels[i];
    float2 v = *(const float2*)&x[i * D_ + lane * 2];
    atomicAdd(&sumx[l * D_ + lane * 2], v.x);
    atomicAdd(&sumx[l * D_ + lane * 2 + 1], v.y);
    if (lane == 0) atomicAdd(&counts[l], 1.0f);
    __hip_bfloat162 p;
    p.x = __float2bfloat16(v.x);
    p.y = __float2bfloat16(v.y);
    *(__hip_bfloat162*)&xb[i * D_ + lane * 2] = p;
    float s = v.x * v.x + v.y * v.y;
    #pragma unroll
    for (int m = 1; m < 64; m <<= 1) s += __shfl_xor(s, m);
    if (lane == 0) xnorm[i] = s;
}

__global__ void center_update(const float* __restrict__ centers, const float* __restrict__ counts,
                              float* __restrict__ sumx_cnew, float* __restrict__ cnorm,
                              __hip_bfloat16* __restrict__ cb, const float* __restrict__ lr) {
    int tid = threadIdx.x;
    int w = tid >> 6, lane = tid & 63;
    int c = blockIdx.x * 4 + w;
    if (c >= C_) {
        *(uint*)&cb[c * D_ + lane * 2] = 0u;
        if (lane == 0) cnorm[c] = 1e30f;
        return;
    }
    float cnt = counts[c];
    float lrv = lr[0];
    float2 cv = *(const float2*)&centers[c * D_ + lane * 2];
    float2 sx = *(const float2*)&sumx_cnew[c * D_ + lane * 2];
    float inv = 1.0f / (1.0f + cnt);
    float nx = cv.x - lrv * (cnt * cv.x - sx.x) * inv;
    float ny = cv.y - lrv * (cnt * cv.y - sx.y) * inv;
    float2 nn = {nx, ny};
    *(float2*)&sumx_cnew[c * D_ + lane * 2] = nn;
    __hip_bfloat162 p;
    p.x = __float2bfloat16(nx);
    p.y = __float2bfloat16(ny);
    *(__hip_bfloat162*)&cb[c * D_ + lane * 2] = p;
    float s = nx * nx + ny * ny;
    #pragma unroll
    for (int m = 1; m < 64; m <<= 1) s += __shfl_xor(s, m);
    if (lane == 0) cnorm[c] = s;
}

__global__ void center_vals_k(const float* __restrict__ x, const int* __restrict__ labels,
                              const float* __restrict__ cnew, float* __restrict__ cent_val) {
    int tid = threadIdx.x;
    int w = tid >> 6, lane = tid & 63;
    int i = blockIdx.x * 4 + w;
    int l = labels[i];
    float2 a = *(const float2*)&x[i * D_ + lane * 2];
    float2 c = *(const float2*)&cnew[l * D_ + lane * 2];
    float dx = a.x - c.x, dy = a.y - c.y;
    float s = dx * dx + dy * dy;
    #pragma unroll
    for (int m = 1; m < 64; m <<= 1) s += __shfl_xor(s, m);
    if (lane == 0) cent_val[i] = s;
}

// Register-resident GEMM + git: no LDS, no barriers.
// Block = 8 waves x 64 A-rows = 512 rows; loops over a strip of 64-col B tiles.
// All 8 waves read the same 16KB B tile -> L1 temporal reuse.
__global__ void __launch_bounds__(512, 2)
gemm_git(const __hip_bfloat16* __restrict__ xb, const __hip_bfloat16* __restrict__ cb,
         const float* __restrict__ xnorm, const float* __restrict__ cnorm,
         float* __restrict__ git_row) {
    int tid = threadIdx.x;
    int w = tid >> 6, lane = tid & 63;
    int lr_ = lane & 15, lg = lane >> 4;
    int strip = blockIdx.x;                 // 16 -> XCD = strip & 7 (B strip L2-resident)
    int bm = blockIdx.y;                    // 16
    int row0 = bm * 512 + w * 64;
    int bn0 = strip * STRIPW;
    int nt = (strip == NSTRIP - 1) ? (NT_TOT - bn0) : STRIPW;

    const s16x8* gx = (const s16x8*)xb;     // row stride = 16 chunks of 16B
    const s16x8* gc = (const s16x8*)cb;

    // A fragments: permanent
    s16x8 af[4][4];
    #pragma unroll
    for (int kk = 0; kk < 4; kk++)
        #pragma unroll
        for (int f = 0; f < 4; f++)
            af[kk][f] = gx[(row0 + f * 16 + lr_) * 16 + kk * 4 + lg];

    float xn1[4][4];
    #pragma unroll
    for (int fm = 0; fm < 4; fm++)
        #pragma unroll
        for (int r = 0; r < 4; r++)
            xn1[fm][r] = 1.0f + xnorm[row0 + fm * 16 + lg * 4 + r];

    float gitsum[4][4] = {};

    for (int t = 0; t < nt; ++t) {
        int cb0 = (bn0 + t) * 64;
        // load whole B tile fragment set first (compiler pipelines 16 loads)
        s16x8 bf[4][4];
        #pragma unroll
        for (int kk = 0; kk < 4; kk++)
            #pragma unroll
            for (int fn = 0; fn < 4; fn++)
                bf[kk][fn] = gc[(cb0 + fn * 16 + lr_) * 16 + kk * 4 + lg];

        f32x4 acc[4][4] = {};
        #pragma unroll
        for (int kk = 0; kk < 4; kk++)
            #pragma unroll
            for (int fm = 0; fm < 4; fm++)
                #pragma unroll
                for (int fn = 0; fn < 4; fn++)
                    acc[fm][fn] = __builtin_amdgcn_mfma_f32_16x16x32_bf16(af[kk][fm], bf[kk][fn], acc[fm][fn], 0, 0, 0);

        float cn[4];
        #pragma unroll
        for (int fn = 0; fn < 4; fn++) cn[fn] = cnorm[cb0 + fn * 16 + lr_];
        #pragma unroll
        for (int fm = 0; fm < 4; fm++)
            #pragma unroll
            for (int r = 0; r < 4; r++) {
                float base = xn1[fm][r];
                #pragma unroll
                for (int fn = 0; fn < 4; fn++)
                    gitsum[fm][r] += __builtin_amdgcn_rcpf(base + cn[fn] - 2.0f * acc[fm][fn][r]);
            }
    }

    #pragma unroll
    for (int fm = 0; fm < 4; fm++)
        #pragma unroll
        for (int r = 0; r < 4; r++) {
            float s = gitsum[fm][r];
            s += __shfl_xor(s, 1); s += __shfl_xor(s, 2);
            s += __shfl_xor(s, 4); s += __shfl_xor(s, 8);
            if (lr_ == 0) atomicAdd(&git_row[row0 + fm * 16 + lg * 4 + r], s);
        }
}

__global__ void final_reduce(const float* __restrict__ cent_val, const float* __restrict__ git_row,
                             float* __restrict__ out) {
    int tid = threadIdx.x;    // 1024
    int w = tid >> 6, lane = tid & 63;
    float cl = 0.0f, gl = 0.0f;
    #pragma unroll
    for (int j = 0; j < 2; j++) {
        int base = (tid * 2 + j) * 4;
        float4 cv = *(const float4*)&cent_val[base];
        float4 gr = *(const float4*)&git_row[base];
        float cvs[4] = {cv.x, cv.y, cv.z, cv.w};
        float grs[4] = {gr.x, gr.y, gr.z, gr.w};
        #pragma unroll
        for (int e = 0; e < 4; e++) {
            float c = cvs[e];
            cl += fminf(fmaxf(c, 1e-12f), 1e12f);
            float g = grs[e] - 1.0f / (1.0f + c);
            gl += fminf(fmaxf(g, 1e-12f), 1e12f);
        }
    }
    #pragma unroll
    for (int m = 1; m < 64; m <<= 1) { cl += __shfl_xor(cl, m); gl += __shfl_xor(gl, m); }
    __shared__ float scl[16], sgl[16];
    if (lane == 0) { scl[w] = cl; sgl[w] = gl; }
    __syncthreads();
    if (tid == 0) {
        float a = 0.0f, b = 0.0f;
        #pragma unroll
        for (int k = 0; k < 16; k++) { a += scl[k]; b += sgl[k]; }
        out[0] = a / (float)B_;
        out[1] = b / (float)B_;
    }
}

extern "C" void kernel_launch(void* const* d_in, const int* in_sizes, int n_in,
                              void* d_out, int out_size, void* d_ws, size_t ws_size,
                              hipStream_t stream) {
    const float* x       = (const float*)d_in[0];
    const int*   labels  = (const int*)d_in[1];
    const float* centers = (const float*)d_in[2];
    const float* lr      = (const float*)d_in[3];

    float* ws       = (float*)d_ws;
    float* counts   = ws;
    float* sumx     = ws + 10240;
    float* git_row  = ws + 1290240;
    float* xnorm    = ws + 1298432;
    float* cent_val = ws + 1306624;
    float* cnorm    = ws + 1314816;
    __hip_bfloat16* xb = (__hip_bfloat16*)((char*)d_ws + 5300224);
    __hip_bfloat16* cb = (__hip_bfloat16*)((char*)d_ws + 7397376);
    float* out = (float*)d_out;

    hipMemsetAsync(d_ws, 0, (size_t)1298432 * 4, stream);

    scatter_xprep<<<B_ / 4, 256, 0, stream>>>(x, labels, counts, sumx, xnorm, xb);
    center_update<<<CPAD / 4, 256, 0, stream>>>(centers, counts, sumx, cnorm, cb, lr);
    center_vals_k<<<B_ / 4, 256, 0, stream>>>(x, labels, sumx, cent_val);
    gemm_git<<<dim3(NSTRIP, 16), 512, 0, stream>>>(xb, cb, xnorm, cnorm, git_row);
    final_reduce<<<1, 1024, 0, stream>>>(cent_val, git_row, out);
}

// Round 4
// 57.576 us; speedup vs baseline: 1.9120x; 1.3441x over previous
//
#include <hip/hip_runtime.h>
#include <hip/hip_bf16.h>

#define B_ 8192
#define C_ 10000
#define D_ 128
#define CPAD 10112      // 158 * 64
#define NPADC 112       // CPAD - C_
#define NT_TOT 158      // 64-col tiles
#define NSTRIP 16
#define STRIPW 10       // strips 0..14 -> 10 tiles, strip 15 -> 8

typedef float f32x4 __attribute__((ext_vector_type(4)));
typedef short s16x8 __attribute__((ext_vector_type(8)));

typedef const __attribute__((address_space(1))) uint32_t gu32;
typedef __attribute__((address_space(3))) uint32_t lu32;

// ---------------- ws layout (float offsets) ----------------
// counts    : [0, 10240)
// sumx/cnew : [10240, 1290240)
// git_row   : [1290240, 1298432)   (zeroed prefix ends here: 5,193,728 B)
// xnorm     : [1298432, 1306624)
// cent_val  : [1306624, 1314816)
// cnorm     : [1314816, 1325056)   (CPAD, pad = 0)
// x_bf16    : byte 5,300,224
// cnew_bf16 : byte 7,397,376       (CPAD rows, pad rows zero)

__global__ void scatter_xprep(const float* __restrict__ x, const int* __restrict__ labels,
                              float* __restrict__ counts, float* __restrict__ sumx,
                              float* __restrict__ xnorm, __hip_bfloat16* __restrict__ xb) {
    int tid = threadIdx.x;
    int w = tid >> 6, lane = tid & 63;
    int i = blockIdx.x * 4 + w;
    int l = labels[i];
    float2 v = *(const float2*)&x[i * D_ + lane * 2];
    atomicAdd(&sumx[l * D_ + lane * 2], v.x);
    atomicAdd(&sumx[l * D_ + lane * 2 + 1], v.y);
    if (lane == 0) atomicAdd(&counts[l], 1.0f);
    __hip_bfloat162 p;
    p.x = __float2bfloat16(v.x);
    p.y = __float2bfloat16(v.y);
    *(__hip_bfloat162*)&xb[i * D_ + lane * 2] = p;
    float s = v.x * v.x + v.y * v.y;
    #pragma unroll
    for (int m = 1; m < 64; m <<= 1) s += __shfl_xor(s, m);
    if (lane == 0) xnorm[i] = s;
}

__global__ void center_update(const float* __restrict__ centers, const float* __restrict__ counts,
                              float* __restrict__ sumx_cnew, float* __restrict__ cnorm,
                              __hip_bfloat16* __restrict__ cb, const float* __restrict__ lr) {
    int tid = threadIdx.x;
    int w = tid >> 6, lane = tid & 63;
    int c = blockIdx.x * 4 + w;
    if (c >= C_) {
        *(uint*)&cb[c * D_ + lane * 2] = 0u;
        if (lane == 0) cnorm[c] = 0.0f;      // pad: zero row, zero norm
        return;
    }
    float cnt = counts[c];
    float lrv = lr[0];
    float2 cv = *(const float2*)&centers[c * D_ + lane * 2];
    float2 sx = *(const float2*)&sumx_cnew[c * D_ + lane * 2];
    float inv = 1.0f / (1.0f + cnt);
    float nx = cv.x - lrv * (cnt * cv.x - sx.x) * inv;
    float ny = cv.y - lrv * (cnt * cv.y - sx.y) * inv;
    float2 nn = {nx, ny};
    *(float2*)&sumx_cnew[c * D_ + lane * 2] = nn;
    __hip_bfloat162 p;
    p.x = __float2bfloat16(nx);
    p.y = __float2bfloat16(ny);
    *(__hip_bfloat162*)&cb[c * D_ + lane * 2] = p;
    float s = nx * nx + ny * ny;
    #pragma unroll
    for (int m = 1; m < 64; m <<= 1) s += __shfl_xor(s, m);
    if (lane == 0) cnorm[c] = s;
}

__global__ void center_vals_k(const float* __restrict__ x, const int* __restrict__ labels,
                              const float* __restrict__ cnew, float* __restrict__ cent_val) {
    int tid = threadIdx.x;
    int w = tid >> 6, lane = tid & 63;
    int i = blockIdx.x * 4 + w;
    int l = labels[i];
    float2 a = *(const float2*)&x[i * D_ + lane * 2];
    float2 c = *(const float2*)&cnew[l * D_ + lane * 2];
    float dx = a.x - c.x, dy = a.y - c.y;
    float s = dx * dx + dy * dy;
    #pragma unroll
    for (int m = 1; m < 64; m <<= 1) s += __shfl_xor(s, m);
    if (lane == 0) cent_val[i] = s;
}

// GEMM + git: A register-resident (8 waves x 64 rows), B double-buffered in LDS
// via async global_load_lds (issued a full tile ahead), XOR-swizzled (pre-swizzled
// global source + swizzled ds_read -> 2-way conflicts only).
__global__ void __launch_bounds__(512)
gemm_git(const __hip_bfloat16* __restrict__ xb, const __hip_bfloat16* __restrict__ cb,
         const float* __restrict__ xnorm, const float* __restrict__ cnorm,
         float* __restrict__ git_row) {
    __shared__ char ldsB[2][16384];   // 64 rows x 16 chunks x 16B, swizzled

    int tid = threadIdx.x;
    int w = tid >> 6, lane = tid & 63;
    int lr_ = lane & 15, lg = lane >> 4;
    int strip = blockIdx.x;
    int bm = blockIdx.y;
    int row0 = bm * 512 + w * 64;
    int bn0 = strip * STRIPW;
    int nt = (strip == NSTRIP - 1) ? (NT_TOT - bn0) : STRIPW;

    const s16x8* gx = (const s16x8*)xb;   // row stride = 16 chunks of 16B

    // A fragments: permanent (64 VGPR)
    s16x8 af[4][4];
    #pragma unroll
    for (int kk = 0; kk < 4; kk++)
        #pragma unroll
        for (int f = 0; f < 4; f++)
            af[kk][f] = gx[(row0 + f * 16 + lr_) * 16 + kk * 4 + lg];

    float xn1[4][4];
    #pragma unroll
    for (int fm = 0; fm < 4; fm++)
        #pragma unroll
        for (int r = 0; r < 4; r++)
            xn1[fm][r] = 1.0f + xnorm[row0 + fm * 16 + lg * 4 + r];

    float gitsum[4][4] = {};

    // staging: thread covers LDS 16B-slots tid and tid+512.
    // LDS slot idx -> (row = idx>>4, ch' = idx&15); source chunk = ch' ^ (row&7).
    const char* gB = (const char*)cb;
    int sr0 = tid >> 4,          sc0 = (tid & 15) ^ (sr0 & 7);
    int sr1 = (tid + 512) >> 4,  sc1 = ((tid + 512) & 15) ^ (sr1 & 7);
    size_t goff0 = (size_t)(sr0 * 16 + sc0) * 16;
    size_t goff1 = (size_t)(sr1 * 16 + sc1) * 16;

    auto stage = [&](int t, int buf) {
        const char* base = gB + (size_t)(bn0 + t) * 64 * 256;   // tile = 64 rows x 256B
        __builtin_amdgcn_global_load_lds((gu32*)(base + goff0),
                                         (lu32*)&ldsB[buf][tid * 16], 16, 0, 0);
        __builtin_amdgcn_global_load_lds((gu32*)(base + goff1),
                                         (lu32*)&ldsB[buf][8192 + tid * 16], 16, 0, 0);
    };

    stage(0, 0);
    __syncthreads();   // emits vmcnt(0) drain before barrier

    int cur = 0;
    for (int t = 0; t < nt; ++t) {
        if (t + 1 < nt) stage(t + 1, cur ^ 1);   // async, lands before next barrier

        int cb0 = (bn0 + t) * 64;
        float cn[4];
        #pragma unroll
        for (int fn = 0; fn < 4; fn++) cn[fn] = cnorm[cb0 + fn * 16 + lr_];

        f32x4 acc[4][4] = {};
        #pragma unroll
        for (int kk = 0; kk < 4; kk++) {
            s16x8 bfk[4];
            int kc = kk * 4 + lg;
            #pragma unroll
            for (int fn = 0; fn < 4; fn++) {
                int row = fn * 16 + lr_;
                int ch = kc ^ (lr_ & 7);          // row&7 == lr_&7
                bfk[fn] = *(const s16x8*)&ldsB[cur][(row * 16 + ch) * 16];
            }
            #pragma unroll
            for (int fm = 0; fm < 4; fm++)
                #pragma unroll
                for (int fn = 0; fn < 4; fn++)
                    acc[fm][fn] = __builtin_amdgcn_mfma_f32_16x16x32_bf16(af[kk][fm], bfk[fn], acc[fm][fn], 0, 0, 0);
        }

        // epilogue: paired reciprocal merge: 1/u + 1/v = (u+v)*rcp(u*v)
        #pragma unroll
        for (int fm = 0; fm < 4; fm++)
            #pragma unroll
            for (int r = 0; r < 4; r++) {
                float base = xn1[fm][r];
                #pragma unroll
                for (int fp = 0; fp < 4; fp += 2) {
                    float u = base + cn[fp]     - 2.0f * acc[fm][fp][r];
                    float v = base + cn[fp + 1] - 2.0f * acc[fm][fp + 1][r];
                    gitsum[fm][r] += (u + v) * __builtin_amdgcn_rcpf(u * v);
                }
            }

        __syncthreads();
        cur ^= 1;
    }

    #pragma unroll
    for (int fm = 0; fm < 4; fm++)
        #pragma unroll
        for (int r = 0; r < 4; r++) {
            float s = gitsum[fm][r];
            s += __shfl_xor(s, 1); s += __shfl_xor(s, 2);
            s += __shfl_xor(s, 4); s += __shfl_xor(s, 8);
            if (lr_ == 0) atomicAdd(&git_row[row0 + fm * 16 + lg * 4 + r], s);
        }
}

__global__ void final_reduce(const float* __restrict__ cent_val, const float* __restrict__ git_row,
                             const float* __restrict__ xnorm, float* __restrict__ out) {
    int tid = threadIdx.x;    // 1024
    int w = tid >> 6, lane = tid & 63;
    float cl = 0.0f, gl = 0.0f;
    #pragma unroll
    for (int j = 0; j < 2; j++) {
        int base = (tid * 2 + j) * 4;
        float4 cv = *(const float4*)&cent_val[base];
        float4 gr = *(const float4*)&git_row[base];
        float4 xn = *(const float4*)&xnorm[base];
        float cvs[4] = {cv.x, cv.y, cv.z, cv.w};
        float grs[4] = {gr.x, gr.y, gr.z, gr.w};
        float xns[4] = {xn.x, xn.y, xn.z, xn.w};
        #pragma unroll
        for (int e = 0; e < 4; e++) {
            float c = cvs[e];
            cl += fminf(fmaxf(c, 1e-12f), 1e12f);
            // remove label column and the 112 pad columns (each contributes 1/(1+xnorm))
            float g = grs[e] - 1.0f / (1.0f + c) - (float)NPADC / (1.0f + xns[e]);
            gl += fminf(fmaxf(g, 1e-12f), 1e12f);
        }
    }
    #pragma unroll
    for (int m = 1; m < 64; m <<= 1) { cl += __shfl_xor(cl, m); gl += __shfl_xor(gl, m); }
    __shared__ float scl[16], sgl[16];
    if (lane == 0) { scl[w] = cl; sgl[w] = gl; }
    __syncthreads();
    if (tid == 0) {
        float a = 0.0f, b = 0.0f;
        #pragma unroll
        for (int k = 0; k < 16; k++) { a += scl[k]; b += sgl[k]; }
        out[0] = a / (float)B_;
        out[1] = b / (float)B_;
    }
}

extern "C" void kernel_launch(void* const* d_in, const int* in_sizes, int n_in,
                              void* d_out, int out_size, void* d_ws, size_t ws_size,
                              hipStream_t stream) {
    const float* x       = (const float*)d_in[0];
    const int*   labels  = (const int*)d_in[1];
    const float* centers = (const float*)d_in[2];
    const float* lr      = (const float*)d_in[3];

    float* ws       = (float*)d_ws;
    float* counts   = ws;
    float* sumx     = ws + 10240;
    float* git_row  = ws + 1290240;
    float* xnorm    = ws + 1298432;
    float* cent_val = ws + 1306624;
    float* cnorm    = ws + 1314816;
    __hip_bfloat16* xb = (__hip_bfloat16*)((char*)d_ws + 5300224);
    __hip_bfloat16* cb = (__hip_bfloat16*)((char*)d_ws + 7397376);
    float* out = (float*)d_out;

    hipMemsetAsync(d_ws, 0, (size_t)1298432 * 4, stream);

    scatter_xprep<<<B_ / 4, 256, 0, stream>>>(x, labels, counts, sumx, xnorm, xb);
    center_update<<<CPAD / 4, 256, 0, stream>>>(centers, counts, sumx, cnorm, cb, lr);
    center_vals_k<<<B_ / 4, 256, 0, stream>>>(x, labels, sumx, cent_val);
    gemm_git<<<dim3(NSTRIP, 16), 512, 0, stream>>>(xb, cb, xnorm, cnorm, git_row);
    final_reduce<<<1, 1024, 0, stream>>>(cent_val, git_row, xnorm, out);
}